// Round 5
// baseline (545.971 us; speedup 1.0000x reference)
//
#include <hip/hip_runtime.h>

typedef short v8s __attribute__((ext_vector_type(8)));
typedef float v4f __attribute__((ext_vector_type(4)));

#define BH 16384             // B*H
#define TBH 33554432         // T*B*H
#define CT 64                // timesteps per chunk
#define NC 32                // 2048 / CT
#define XP 264               // x/W LDS row pitch in shorts (256 + 8 pad)
#define WP 72                // xW LDS row pitch in floats (64 + 8 pad)

__device__ __forceinline__ ushort f2bf(float f) {
  // round-to-nearest-even fp32 -> bf16 (inputs finite)
  uint u = __float_as_uint(f);
  u += 0x7FFF + ((u >> 16) & 1);
  return (ushort)(u >> 16);
}

// One block per (b, h-quarter). Pipeline per 64-t chunk:
//   phase 1: wave 0 scans chunk c from XWs (serial recurrence, streams h to global);
//            waves 1-3 stage x chunk c+2 (fp32->bf16) into Xs[c&1]
//   phase 2: all waves MFMA chunk c+1 from Xs[(c+1)&1] into XWs
// Staged chunk c+2 is consumed one full iteration later -> HBM latency has a
// whole phase to land. No cross-block communication.
__global__ __launch_bounds__(256) void indrnn_fused(
    const float* __restrict__ x,
    const float* __restrict__ h0,
    const float* __restrict__ W,
    const float* __restrict__ w_hh,
    float* __restrict__ out)
{
  __shared__ ushort Ws[64 * XP];         // W quarter, bf16       (~34 KB)
  __shared__ ushort Xs[2][CT * XP];      // x chunk double-buffer (~68 KB)
  __shared__ float  XWs[CT * WP];        // xW chunk, fp32        (~18 KB)

  const int tid  = threadIdx.x;
  const int wave = tid >> 6;
  const int lane = tid & 63;

  // Swizzle so the 4 blocks sharing one b land on the same XCD (blk&7 ~ XCD).
  const int xcd  = blockIdx.x & 7;
  const int q    = blockIdx.x >> 3;      // 0..31
  const int b    = xcd * 8 + (q >> 2);   // 0..63
  const int hq   = q & 3;                // h-quarter
  const int base = b * 256 + hq * 64;    // flat channel base in [B*H]

  const int l15 = lane & 15;
  const int lhi = lane >> 4;             // 0..3

  // ---- prologue: stage W quarter (64 x 256) and x chunks 0,1 ----
  // ROWS ARE 256 WIDE = 64 float4s each (round-4 bug: only 16 were staged).
  for (int i = tid; i < 64 * 64; i += 256) {
    int r  = i >> 6;
    int c4 = (i & 63) * 4;
    float4 a4 = *(const float4*)(W + (size_t)(hq * 64 + r) * 256 + c4);
    *(ushort4*)(Ws + r * XP + c4) =
        make_ushort4(f2bf(a4.x), f2bf(a4.y), f2bf(a4.z), f2bf(a4.w));
  }
  #pragma unroll
  for (int pc = 0; pc < 2; ++pc) {
    const float* src = x + (size_t)pc * CT * BH + b * 256;
    ushort* dst = Xs[pc];
    for (int i = tid; i < CT * 64; i += 256) {
      int t  = i >> 6;
      int c4 = (i & 63) * 4;
      float4 a4 = *(const float4*)(src + (size_t)t * BH + c4);
      *(ushort4*)(dst + t * XP + c4) =
          make_ushort4(f2bf(a4.x), f2bf(a4.y), f2bf(a4.z), f2bf(a4.w));
    }
  }
  __syncthreads();

  const float w = w_hh[hq * 64 + lane];
  float h = (wave == 0) ? h0[base + lane] : 0.0f;

  // ---- MFMA chunk 0 from Xs[0] ----
  {
    v4f acc[4] = {};
    #pragma unroll
    for (int kk = 0; kk < 8; ++kk) {
      const int koff = kk * 32 + lhi * 8;
      v8s af = *(const v8s*)(Xs[0] + (wave * 16 + l15) * XP + koff);
      #pragma unroll
      for (int nt = 0; nt < 4; ++nt) {
        v8s bf = *(const v8s*)(Ws + (nt * 16 + l15) * XP + koff);
        acc[nt] = __builtin_amdgcn_mfma_f32_16x16x32_bf16(af, bf, acc[nt], 0, 0, 0);
      }
    }
    #pragma unroll
    for (int nt = 0; nt < 4; ++nt)
      #pragma unroll
      for (int r = 0; r < 4; ++r)
        XWs[(wave * 16 + lhi * 4 + r) * WP + nt * 16 + l15] = acc[nt][r];
  }
  __syncthreads();

  // ---- main pipeline ----
  for (int c = 0; c < NC; ++c) {
    if (wave == 0) {
      // serial scan of chunk c out of LDS; stream h to global
      float* po = out + (size_t)c * CT * BH + base;
      #pragma unroll 8
      for (int t = 0; t < CT; ++t) {
        float xv = XWs[t * WP + lane];
        h = fmaxf(fmaf(h, w, xv), 0.0f);
        po[(size_t)t * BH + lane] = h;
      }
    } else if (c + 2 < NC) {
      // stage x chunk c+2 into Xs[c&1] (consumed by MFMA at iter c+1)
      const float* src = x + (size_t)(c + 2) * CT * BH + b * 256;
      ushort* dst = Xs[c & 1];
      for (int i = tid - 64; i < CT * 64; i += 192) {
        int t  = i >> 6;
        int c4 = (i & 63) * 4;
        float4 a4 = *(const float4*)(src + (size_t)t * BH + c4);
        *(ushort4*)(dst + t * XP + c4) =
            make_ushort4(f2bf(a4.x), f2bf(a4.y), f2bf(a4.z), f2bf(a4.w));
      }
    }
    __syncthreads();

    if (c + 1 < NC) {
      // MFMA chunk c+1 from Xs[(c+1)&1] (staged at iter c-1; XWs free after barrier)
      const ushort* xb = Xs[(c + 1) & 1];
      v4f acc[4] = {};
      #pragma unroll
      for (int kk = 0; kk < 8; ++kk) {
        const int koff = kk * 32 + lhi * 8;
        v8s af = *(const v8s*)(xb + (wave * 16 + l15) * XP + koff);
        #pragma unroll
        for (int nt = 0; nt < 4; ++nt) {
          v8s bf = *(const v8s*)(Ws + (nt * 16 + l15) * XP + koff);
          acc[nt] = __builtin_amdgcn_mfma_f32_16x16x32_bf16(af, bf, acc[nt], 0, 0, 0);
        }
      }
      #pragma unroll
      for (int nt = 0; nt < 4; ++nt)
        #pragma unroll
        for (int r = 0; r < 4; ++r)
          XWs[(wave * 16 + lhi * 4 + r) * WP + nt * 16 + l15] = acc[nt][r];
      __syncthreads();
    }
  }

  if (wave == 0)
    out[(size_t)TBH + base + lane] = h;   // h_last
}

extern "C" void kernel_launch(void* const* d_in, const int* in_sizes, int n_in,
                              void* d_out, int out_size, void* d_ws, size_t ws_size,
                              hipStream_t stream) {
  const float* x    = (const float*)d_in[0];   // [2048, 64, 256]
  const float* h0   = (const float*)d_in[1];   // [1, 64, 256]
  const float* W_ih = (const float*)d_in[2];   // [256, 256]
  const float* w_hh = (const float*)d_in[3];   // [256]
  float* out = (float*)d_out;                  // [T,B,H] ++ [1,B,H]

  indrnn_fused<<<dim3(256), dim3(256), 0, stream>>>(x, h0, W_ih, w_hh, out);
}